// Round 2
// baseline (519.042 us; speedup 1.0000x reference)
//
#include <hip/hip_runtime.h>
#include <math.h>

#define NBATCH 64
#define Q      1000
#define C      1203
#define QC     1203000      // Q*C
#define QC4    300750       // QC/4
#define K      100
#define NBINS  2048         // top 11 bits of monotonic key (fallback path)
#define CAP    1024         // candidate capacity per batch
#define BPB    32           // blocks per batch for the scan pass
#define BS     256
#define TLOGIT 3.4f         // fast-path collect threshold (exp ~405/batch for N(0,1))

// monotonic uint key: key increasing <=> float increasing
__device__ __forceinline__ unsigned int mono_key(float x) {
    unsigned int u = __float_as_uint(x);
    return u ^ ((u >> 31) ? 0xFFFFFFFFu : 0x80000000u);
}
__device__ __forceinline__ float key_to_float(unsigned int k) {
    unsigned int u = (k & 0x80000000u) ? (k ^ 0x80000000u) : ~k;
    return __uint_as_float(u);
}

// Tiny init: only the per-batch fast-path counters need zeroing.
__global__ void pp_zero(unsigned int* __restrict__ cnt) {
    if (threadIdx.x < NBATCH) cnt[threadIdx.x] = 0u;
}

// Single full read of logits; collect candidates >= fixed logit threshold.
// Loop body kept BYTE-IDENTICAL to the proven 461us baseline pass1
// (four independent rare branches; no fmax guard -- that guard cost +57us).
__global__ void __launch_bounds__(BS) pp_pass1(const float* __restrict__ logits,
                                               unsigned int* __restrict__ cnt,
                                               uint2* __restrict__ cand) {
    int b   = blockIdx.x / BPB;
    int sub = blockIdx.x % BPB;
    const float4* src = (const float4*)(logits + (size_t)b * QC);
    uint2* cb = cand + (size_t)b * CAP;
    for (int i = sub * BS + threadIdx.x; i < QC4; i += BPB * BS) {
        float4 v = src[i];
        unsigned int base = 4u * (unsigned int)i;
        if (v.x >= TLOGIT) { unsigned int s = atomicAdd(&cnt[b], 1u); if (s < CAP) cb[s] = make_uint2(mono_key(v.x), base + 0u); }
        if (v.y >= TLOGIT) { unsigned int s = atomicAdd(&cnt[b], 1u); if (s < CAP) cb[s] = make_uint2(mono_key(v.y), base + 1u); }
        if (v.z >= TLOGIT) { unsigned int s = atomicAdd(&cnt[b], 1u); if (s < CAP) cb[s] = make_uint2(mono_key(v.z), base + 2u); }
        if (v.w >= TLOGIT) { unsigned int s = atomicAdd(&cnt[b], 1u); if (s < CAP) cb[s] = make_uint2(mono_key(v.w), base + 3u); }
    }
}

// One block per batch. Fast path: rank candidates, write outputs.
// Fallback (statistically never taken, kept for exactness): block-local
// histogram select over the batch's logits, then collect + rank.
__global__ void __launch_bounds__(BS) pp_finish(const unsigned int* __restrict__ cnt,
                                                const uint2* __restrict__ cand,
                                                const float* __restrict__ logits,
                                                const float* __restrict__ bbox,
                                                const float* __restrict__ tsizes,
                                                float* __restrict__ out) {
    __shared__ uint2 sc[CAP];
    __shared__ unsigned int lh[NBINS];
    __shared__ unsigned int sn;
    __shared__ unsigned int tk_s;

    int b = blockIdx.x;
    unsigned int n = cnt[b];

    if (n >= (unsigned int)K && n <= (unsigned int)CAP) {
        // ---- fast path ----
        const uint2* cb = cand + (size_t)b * CAP;
        for (unsigned int i = threadIdx.x; i < n; i += BS) sc[i] = cb[i];
        __syncthreads();
    } else {
        // ---- exact fallback: block-local histogram over this batch ----
        for (int i = threadIdx.x; i < NBINS; i += BS) lh[i] = 0u;
        __syncthreads();
        const float4* src = (const float4*)(logits + (size_t)b * QC);
        for (int i = threadIdx.x; i < QC4; i += BS) {
            float4 v = src[i];
            atomicAdd(&lh[mono_key(v.x) >> 21], 1u);
            atomicAdd(&lh[mono_key(v.y) >> 21], 1u);
            atomicAdd(&lh[mono_key(v.z) >> 21], 1u);
            atomicAdd(&lh[mono_key(v.w) >> 21], 1u);
        }
        __syncthreads();
        if (threadIdx.x == 0) {
            unsigned int cum = 0;
            int tb = 0;
            for (int i = NBINS - 1; i >= 0; --i) {
                cum += lh[i];
                if (cum >= (unsigned int)K) { tb = i; break; }
            }
            tk_s = ((unsigned int)tb) << 21;
            sn = 0u;
        }
        __syncthreads();
        unsigned int tk = tk_s;
        for (int i = threadIdx.x; i < QC4; i += BS) {
            float4 v = src[i];
            unsigned int base = 4u * (unsigned int)i;
            unsigned int k0 = mono_key(v.x);
            unsigned int k1 = mono_key(v.y);
            unsigned int k2 = mono_key(v.z);
            unsigned int k3 = mono_key(v.w);
            if (k0 >= tk) { unsigned int s = atomicAdd(&sn, 1u); if (s < CAP) sc[s] = make_uint2(k0, base + 0u); }
            if (k1 >= tk) { unsigned int s = atomicAdd(&sn, 1u); if (s < CAP) sc[s] = make_uint2(k1, base + 1u); }
            if (k2 >= tk) { unsigned int s = atomicAdd(&sn, 1u); if (s < CAP) sc[s] = make_uint2(k2, base + 2u); }
            if (k3 >= tk) { unsigned int s = atomicAdd(&sn, 1u); if (s < CAP) sc[s] = make_uint2(k3, base + 3u); }
        }
        __syncthreads();
        n = sn;
        if (n > CAP) n = CAP;
    }

    // ---- exact top-K among candidates: rank by (key desc, idx asc) ----
    float img_h = tsizes[2 * b + 0];
    float img_w = tsizes[2 * b + 1];
    float* scores = out;
    float* labels = out + NBATCH * K;
    float* boxes  = out + 2 * NBATCH * K;
    for (unsigned int i = threadIdx.x; i < n; i += BS) {
        uint2 me = sc[i];
        int rank = 0;
        for (unsigned int j = 0; j < n; ++j) {
            uint2 o = sc[j];
            if (o.x > me.x || (o.x == me.x && o.y < me.y)) rank++;
        }
        if (rank < K) {
            float v = key_to_float(me.x);
            double sd = 1.0 / (1.0 + exp(-(double)v));
            scores[b * K + rank] = (float)sd;
            unsigned int idx = me.y;
            unsigned int q   = idx / C;
            unsigned int lab = idx - q * C;
            labels[b * K + rank] = (float)lab;
            const float* bb = bbox + ((size_t)b * Q + q) * 4;
            float cx = bb[0], cy = bb[1], w = bb[2], h = bb[3];
            float* o = boxes + ((size_t)b * K + (size_t)rank) * 4;
            o[0] = (cx - 0.5f * w) * img_w;
            o[1] = (cy - 0.5f * h) * img_h;
            o[2] = (cx + 0.5f * w) * img_w;
            o[3] = (cy + 0.5f * h) * img_h;
        }
    }
}

extern "C" void kernel_launch(void* const* d_in, const int* in_sizes, int n_in,
                              void* d_out, int out_size, void* d_ws, size_t ws_size,
                              hipStream_t stream) {
    const float* logits = (const float*)d_in[0];   // 64*1000*1203
    const float* bbox   = (const float*)d_in[1];   // 64*1000*4
    const float* tsizes = (const float*)d_in[2];   // 64*2
    float* out = (float*)d_out;

    char* ws = (char*)d_ws;
    unsigned int* cnt  = (unsigned int*)(ws);          // 256 B
    uint2*        cand = (uint2*)(ws + 1024);          // 512 KiB

    pp_zero<<<1, 64, 0, stream>>>(cnt);
    pp_pass1<<<NBATCH * BPB, BS, 0, stream>>>(logits, cnt, cand);
    pp_finish<<<NBATCH, BS, 0, stream>>>(cnt, cand, logits, bbox, tsizes, out);
}

// Round 3
// 461.773 us; speedup vs baseline: 1.1240x; 1.1240x over previous
//
#include <hip/hip_runtime.h>
#include <math.h>

#define NBATCH 64
#define Q      1000
#define C      1203
#define QC     1203000      // Q*C
#define QC4    300750       // QC/4
#define K      100
#define NBINS  2048         // top 11 bits of monotonic key (fallback path)
#define CAP    1024         // candidate capacity per batch
#define BPB    32           // blocks per batch for the big passes
#define BS     256
#define TLOGIT 3.4f         // fast-path collect threshold (exp ~405/batch for N(0,1))

// monotonic uint key: key increasing <=> float increasing
__device__ __forceinline__ unsigned int mono_key(float x) {
    unsigned int u = __float_as_uint(x);
    return u ^ ((u >> 31) ? 0xFFFFFFFFu : 0x80000000u);
}
__device__ __forceinline__ float key_to_float(unsigned int k) {
    unsigned int u = (k & 0x80000000u) ? (k ^ 0x80000000u) : ~k;
    return __uint_as_float(u);
}

__global__ void __launch_bounds__(BS) zero_kernel(unsigned int* hist, unsigned int* cnt,
                                                  unsigned int* flags) {
    int i = blockIdx.x * BS + threadIdx.x;
    if (i < NBATCH * NBINS) hist[i] = 0u;
    if (i < NBATCH) { cnt[i] = 0u; flags[i] = 0u; }
}

// Fast path: single full read; collect candidates >= fixed logit threshold.
__global__ void __launch_bounds__(BS) pass1_kernel(const float* __restrict__ logits,
                                                   unsigned int* __restrict__ cnt,
                                                   uint2* __restrict__ cand) {
    int b   = blockIdx.x / BPB;
    int sub = blockIdx.x % BPB;
    const float4* src = (const float4*)(logits + (size_t)b * QC);
    uint2* cb = cand + (size_t)b * CAP;
    for (int i = sub * BS + threadIdx.x; i < QC4; i += BPB * BS) {
        float4 v = src[i];
        unsigned int base = 4u * (unsigned int)i;
        if (v.x >= TLOGIT) { unsigned int s = atomicAdd(&cnt[b], 1u); if (s < CAP) cb[s] = make_uint2(mono_key(v.x), base + 0u); }
        if (v.y >= TLOGIT) { unsigned int s = atomicAdd(&cnt[b], 1u); if (s < CAP) cb[s] = make_uint2(mono_key(v.y), base + 1u); }
        if (v.z >= TLOGIT) { unsigned int s = atomicAdd(&cnt[b], 1u); if (s < CAP) cb[s] = make_uint2(mono_key(v.z), base + 2u); }
        if (v.w >= TLOGIT) { unsigned int s = atomicAdd(&cnt[b], 1u); if (s < CAP) cb[s] = make_uint2(mono_key(v.w), base + 3u); }
    }
}

// Check fast path validity per batch; arm fallback where it failed.
__global__ void flag_kernel(unsigned int* __restrict__ cnt,
                            unsigned int* __restrict__ flags) {
    int b = threadIdx.x;
    if (b < NBATCH) {
        unsigned int n = cnt[b];
        unsigned int f = (n < (unsigned int)K || n > (unsigned int)CAP) ? 1u : 0u;
        flags[b] = f;
        if (f) cnt[b] = 0u;   // fallback collect restarts this batch
    }
}

// ---- Fallback path (exact histogram select); early-exits unless flagged ----
__global__ void __launch_bounds__(BS) hist_kernel(const float* __restrict__ logits,
                                                  const unsigned int* __restrict__ flags,
                                                  unsigned int* __restrict__ hist) {
    int b = blockIdx.x / BPB;
    if (!flags[b]) return;
    __shared__ unsigned int lh[NBINS];
    int sub = blockIdx.x % BPB;
    for (int i = threadIdx.x; i < NBINS; i += BS) lh[i] = 0u;
    __syncthreads();
    const float4* src = (const float4*)(logits + (size_t)b * QC);
    for (int i = sub * BS + threadIdx.x; i < QC4; i += BPB * BS) {
        float4 v = src[i];
        atomicAdd(&lh[mono_key(v.x) >> 21], 1u);
        atomicAdd(&lh[mono_key(v.y) >> 21], 1u);
        atomicAdd(&lh[mono_key(v.z) >> 21], 1u);
        atomicAdd(&lh[mono_key(v.w) >> 21], 1u);
    }
    __syncthreads();
    unsigned int* gh = hist + (size_t)b * NBINS;
    for (int i = threadIdx.x; i < NBINS; i += BS) {
        unsigned int c = lh[i];
        if (c) atomicAdd(&gh[i], c);
    }
}

__global__ void __launch_bounds__(BS) select_kernel(const unsigned int* __restrict__ hist,
                                                    const unsigned int* __restrict__ flags,
                                                    unsigned int* __restrict__ thresh) {
    int b = blockIdx.x;
    if (!flags[b]) return;
    __shared__ unsigned int lh[NBINS];
    __shared__ unsigned int seg[BS];
    const unsigned int* gh = hist + (size_t)b * NBINS;
    for (int j = 0; j < NBINS / BS; ++j)
        lh[threadIdx.x + j * BS] = gh[threadIdx.x + j * BS];
    __syncthreads();
    unsigned int segsum = 0;
    for (int j = 0; j < NBINS / BS; ++j) segsum += lh[threadIdx.x * (NBINS / BS) + j];
    seg[threadIdx.x] = segsum;
    __syncthreads();
    if (threadIdx.x == 0) {
        unsigned int cum = 0;
        int tb = 0;
        for (int sgi = BS - 1; sgi >= 0; --sgi) {
            if (cum + seg[sgi] >= K) {
                int hi = sgi * (NBINS / BS) + (NBINS / BS) - 1;
                int lo = sgi * (NBINS / BS);
                for (int i = hi; i >= lo; --i) {
                    cum += lh[i];
                    if (cum >= K) { tb = i; break; }
                }
                break;
            }
            cum += seg[sgi];
        }
        thresh[b] = ((unsigned int)tb) << 21;
    }
}

__global__ void __launch_bounds__(BS) collect_kernel(const float* __restrict__ logits,
                                                     const unsigned int* __restrict__ flags,
                                                     const unsigned int* __restrict__ thresh,
                                                     unsigned int* __restrict__ cnt,
                                                     uint2* __restrict__ cand) {
    int b = blockIdx.x / BPB;
    if (!flags[b]) return;
    int sub = blockIdx.x % BPB;
    unsigned int tk = thresh[b];
    const float4* src = (const float4*)(logits + (size_t)b * QC);
    uint2* cb = cand + (size_t)b * CAP;
    for (int i = sub * BS + threadIdx.x; i < QC4; i += BPB * BS) {
        float4 v = src[i];
        unsigned int base = 4u * (unsigned int)i;
        unsigned int k0 = mono_key(v.x);
        unsigned int k1 = mono_key(v.y);
        unsigned int k2 = mono_key(v.z);
        unsigned int k3 = mono_key(v.w);
        if (k0 >= tk) { unsigned int s = atomicAdd(&cnt[b], 1u); if (s < CAP) cb[s] = make_uint2(k0, base + 0u); }
        if (k1 >= tk) { unsigned int s = atomicAdd(&cnt[b], 1u); if (s < CAP) cb[s] = make_uint2(k1, base + 1u); }
        if (k2 >= tk) { unsigned int s = atomicAdd(&cnt[b], 1u); if (s < CAP) cb[s] = make_uint2(k2, base + 2u); }
        if (k3 >= tk) { unsigned int s = atomicAdd(&cnt[b], 1u); if (s < CAP) cb[s] = make_uint2(k3, base + 3u); }
    }
}

// Exact top-K among candidates: rank by (key desc, idx asc); write outputs.
__global__ void __launch_bounds__(BS) output_kernel(const unsigned int* __restrict__ cnt,
                                                    const uint2* __restrict__ cand,
                                                    const float* __restrict__ bbox,
                                                    const float* __restrict__ tsizes,
                                                    float* __restrict__ out) {
    __shared__ uint2 sc[CAP];
    int b = blockIdx.x;
    unsigned int n = cnt[b];
    if (n > CAP) n = CAP;
    const uint2* cb = cand + (size_t)b * CAP;
    for (unsigned int i = threadIdx.x; i < n; i += BS) sc[i] = cb[i];
    __syncthreads();
    float img_h = tsizes[2 * b + 0];
    float img_w = tsizes[2 * b + 1];
    float* scores = out;
    float* labels = out + NBATCH * K;
    float* boxes  = out + 2 * NBATCH * K;
    for (unsigned int i = threadIdx.x; i < n; i += BS) {
        uint2 me = sc[i];
        int rank = 0;
        for (unsigned int j = 0; j < n; ++j) {
            uint2 o = sc[j];
            if (o.x > me.x || (o.x == me.x && o.y < me.y)) rank++;
        }
        if (rank < K) {
            float v = key_to_float(me.x);
            double sd = 1.0 / (1.0 + exp(-(double)v));
            scores[b * K + rank] = (float)sd;
            unsigned int idx = me.y;
            unsigned int q   = idx / C;
            unsigned int lab = idx - q * C;
            labels[b * K + rank] = (float)lab;
            const float* bb = bbox + ((size_t)b * Q + q) * 4;
            float cx = bb[0], cy = bb[1], w = bb[2], h = bb[3];
            float* o = boxes + ((size_t)b * K + (size_t)rank) * 4;
            o[0] = (cx - 0.5f * w) * img_w;
            o[1] = (cy - 0.5f * h) * img_h;
            o[2] = (cx + 0.5f * w) * img_w;
            o[3] = (cy + 0.5f * h) * img_h;
        }
    }
}

extern "C" void kernel_launch(void* const* d_in, const int* in_sizes, int n_in,
                              void* d_out, int out_size, void* d_ws, size_t ws_size,
                              hipStream_t stream) {
    const float* logits = (const float*)d_in[0];   // 64*1000*1203
    const float* bbox   = (const float*)d_in[1];   // 64*1000*4
    const float* tsizes = (const float*)d_in[2];   // 64*2
    float* out = (float*)d_out;

    char* ws = (char*)d_ws;
    unsigned int* hist   = (unsigned int*)(ws);                       // 512 KiB
    unsigned int* cnt    = (unsigned int*)(ws + 524288);              // 256 B
    unsigned int* thresh = (unsigned int*)(ws + 524544);              // 256 B
    unsigned int* flags  = (unsigned int*)(ws + 524800);              // 256 B
    uint2*        cand   = (uint2*)(ws + 525056);                     // 512 KiB

    int zgrid = (NBATCH * NBINS + BS - 1) / BS;
    zero_kernel<<<zgrid, BS, 0, stream>>>(hist, cnt, flags);
    pass1_kernel<<<NBATCH * BPB, BS, 0, stream>>>(logits, cnt, cand);
    flag_kernel<<<1, 64, 0, stream>>>(cnt, flags);
    hist_kernel<<<NBATCH * BPB, BS, 0, stream>>>(logits, flags, hist);
    select_kernel<<<NBATCH, BS, 0, stream>>>(hist, flags, thresh);
    collect_kernel<<<NBATCH * BPB, BS, 0, stream>>>(logits, flags, thresh, cnt, cand);
    output_kernel<<<NBATCH, BS, 0, stream>>>(cnt, cand, bbox, tsizes, out);
}

// Round 4
// 456.629 us; speedup vs baseline: 1.1367x; 1.0113x over previous
//
#include <hip/hip_runtime.h>
#include <math.h>

#define NBATCH 64
#define Q      1000
#define C      1203
#define QC     1203000      // Q*C
#define QC4    300750       // QC/4
#define K      100
#define NBINS  2048         // top 11 bits of monotonic key (fallback path)
#define CAP    1024         // candidate capacity per batch
#define BPB    32           // blocks per batch for the scan pass
#define BS     256
#define TLOGIT 3.4f         // fast-path collect threshold (exp ~405/batch for N(0,1))

// monotonic uint key: key increasing <=> float increasing
__device__ __forceinline__ unsigned int mono_key(float x) {
    unsigned int u = __float_as_uint(x);
    return u ^ ((u >> 31) ? 0xFFFFFFFFu : 0x80000000u);
}
__device__ __forceinline__ float key_to_float(unsigned int k) {
    unsigned int u = (k & 0x80000000u) ? (k ^ 0x80000000u) : ~k;
    return __uint_as_float(u);
}

// Tiny init: only per-batch counters (fallback hist is LDS-local now).
__global__ void pp_zero(unsigned int* __restrict__ cnt) {
    if (threadIdx.x < NBATCH) cnt[threadIdx.x] = 0u;
}

// Fast path: single full read; collect candidates >= fixed logit threshold.
// BYTE-IDENTICAL to the proven 461.8us baseline pass1_kernel.
__global__ void __launch_bounds__(BS) pass1_kernel(const float* __restrict__ logits,
                                                   unsigned int* __restrict__ cnt,
                                                   uint2* __restrict__ cand) {
    int b   = blockIdx.x / BPB;
    int sub = blockIdx.x % BPB;
    const float4* src = (const float4*)(logits + (size_t)b * QC);
    uint2* cb = cand + (size_t)b * CAP;
    for (int i = sub * BS + threadIdx.x; i < QC4; i += BPB * BS) {
        float4 v = src[i];
        unsigned int base = 4u * (unsigned int)i;
        if (v.x >= TLOGIT) { unsigned int s = atomicAdd(&cnt[b], 1u); if (s < CAP) cb[s] = make_uint2(mono_key(v.x), base + 0u); }
        if (v.y >= TLOGIT) { unsigned int s = atomicAdd(&cnt[b], 1u); if (s < CAP) cb[s] = make_uint2(mono_key(v.y), base + 1u); }
        if (v.z >= TLOGIT) { unsigned int s = atomicAdd(&cnt[b], 1u); if (s < CAP) cb[s] = make_uint2(mono_key(v.z), base + 2u); }
        if (v.w >= TLOGIT) { unsigned int s = atomicAdd(&cnt[b], 1u); if (s < CAP) cb[s] = make_uint2(mono_key(v.w), base + 3u); }
    }
}

// Self-contained exact fallback; one block per batch; early-exits when the
// fast path was valid (always true for this workload's statistics).
// If invalid: block-local LDS histogram select over this batch's logits,
// recollect candidates into cand, rewrite cnt. Exactness preserved.
__global__ void __launch_bounds__(BS) fallback_kernel(const float* __restrict__ logits,
                                                      unsigned int* __restrict__ cnt,
                                                      uint2* __restrict__ cand) {
    int b = blockIdx.x;
    unsigned int n0 = cnt[b];
    if (n0 >= (unsigned int)K && n0 <= (unsigned int)CAP) return;

    __shared__ unsigned int lh[NBINS];
    __shared__ uint2 sc[CAP];
    __shared__ unsigned int sn;
    __shared__ unsigned int tk_s;

    for (int i = threadIdx.x; i < NBINS; i += BS) lh[i] = 0u;
    __syncthreads();
    const float4* src = (const float4*)(logits + (size_t)b * QC);
    for (int i = threadIdx.x; i < QC4; i += BS) {
        float4 v = src[i];
        atomicAdd(&lh[mono_key(v.x) >> 21], 1u);
        atomicAdd(&lh[mono_key(v.y) >> 21], 1u);
        atomicAdd(&lh[mono_key(v.z) >> 21], 1u);
        atomicAdd(&lh[mono_key(v.w) >> 21], 1u);
    }
    __syncthreads();
    if (threadIdx.x == 0) {
        unsigned int cum = 0;
        int tb = 0;
        for (int i = NBINS - 1; i >= 0; --i) {
            cum += lh[i];
            if (cum >= (unsigned int)K) { tb = i; break; }
        }
        tk_s = ((unsigned int)tb) << 21;
        sn = 0u;
    }
    __syncthreads();
    unsigned int tk = tk_s;
    for (int i = threadIdx.x; i < QC4; i += BS) {
        float4 v = src[i];
        unsigned int base = 4u * (unsigned int)i;
        unsigned int k0 = mono_key(v.x);
        unsigned int k1 = mono_key(v.y);
        unsigned int k2 = mono_key(v.z);
        unsigned int k3 = mono_key(v.w);
        if (k0 >= tk) { unsigned int s = atomicAdd(&sn, 1u); if (s < CAP) sc[s] = make_uint2(k0, base + 0u); }
        if (k1 >= tk) { unsigned int s = atomicAdd(&sn, 1u); if (s < CAP) sc[s] = make_uint2(k1, base + 1u); }
        if (k2 >= tk) { unsigned int s = atomicAdd(&sn, 1u); if (s < CAP) sc[s] = make_uint2(k2, base + 2u); }
        if (k3 >= tk) { unsigned int s = atomicAdd(&sn, 1u); if (s < CAP) sc[s] = make_uint2(k3, base + 3u); }
    }
    __syncthreads();
    unsigned int m = sn;
    if (m > CAP) m = CAP;
    uint2* cb = cand + (size_t)b * CAP;
    for (unsigned int i = threadIdx.x; i < m; i += BS) cb[i] = sc[i];
    if (threadIdx.x == 0) cnt[b] = m;
}

// Exact top-K among candidates: rank by (key desc, idx asc); write outputs.
// BYTE-IDENTICAL to the proven 461.8us baseline output_kernel.
__global__ void __launch_bounds__(BS) output_kernel(const unsigned int* __restrict__ cnt,
                                                    const uint2* __restrict__ cand,
                                                    const float* __restrict__ bbox,
                                                    const float* __restrict__ tsizes,
                                                    float* __restrict__ out) {
    __shared__ uint2 sc[CAP];
    int b = blockIdx.x;
    unsigned int n = cnt[b];
    if (n > CAP) n = CAP;
    const uint2* cb = cand + (size_t)b * CAP;
    for (unsigned int i = threadIdx.x; i < n; i += BS) sc[i] = cb[i];
    __syncthreads();
    float img_h = tsizes[2 * b + 0];
    float img_w = tsizes[2 * b + 1];
    float* scores = out;
    float* labels = out + NBATCH * K;
    float* boxes  = out + 2 * NBATCH * K;
    for (unsigned int i = threadIdx.x; i < n; i += BS) {
        uint2 me = sc[i];
        int rank = 0;
        for (unsigned int j = 0; j < n; ++j) {
            uint2 o = sc[j];
            if (o.x > me.x || (o.x == me.x && o.y < me.y)) rank++;
        }
        if (rank < K) {
            float v = key_to_float(me.x);
            double sd = 1.0 / (1.0 + exp(-(double)v));
            scores[b * K + rank] = (float)sd;
            unsigned int idx = me.y;
            unsigned int q   = idx / C;
            unsigned int lab = idx - q * C;
            labels[b * K + rank] = (float)lab;
            const float* bb = bbox + ((size_t)b * Q + q) * 4;
            float cx = bb[0], cy = bb[1], w = bb[2], h = bb[3];
            float* o = boxes + ((size_t)b * K + (size_t)rank) * 4;
            o[0] = (cx - 0.5f * w) * img_w;
            o[1] = (cy - 0.5f * h) * img_h;
            o[2] = (cx + 0.5f * w) * img_w;
            o[3] = (cy + 0.5f * h) * img_h;
        }
    }
}

extern "C" void kernel_launch(void* const* d_in, const int* in_sizes, int n_in,
                              void* d_out, int out_size, void* d_ws, size_t ws_size,
                              hipStream_t stream) {
    const float* logits = (const float*)d_in[0];   // 64*1000*1203
    const float* bbox   = (const float*)d_in[1];   // 64*1000*4
    const float* tsizes = (const float*)d_in[2];   // 64*2
    float* out = (float*)d_out;

    char* ws = (char*)d_ws;
    unsigned int* cnt  = (unsigned int*)(ws);          // 256 B
    uint2*        cand = (uint2*)(ws + 1024);          // 512 KiB

    pp_zero<<<1, 64, 0, stream>>>(cnt);
    pass1_kernel<<<NBATCH * BPB, BS, 0, stream>>>(logits, cnt, cand);
    fallback_kernel<<<NBATCH, BS, 0, stream>>>(logits, cnt, cand);
    output_kernel<<<NBATCH, BS, 0, stream>>>(cnt, cand, bbox, tsizes, out);
}

// Round 5
// 437.618 us; speedup vs baseline: 1.1861x; 1.0434x over previous
//
#include <hip/hip_runtime.h>
#include <math.h>

#define NBATCH 64
#define Q      1000
#define C      1203
#define QC     1203000      // Q*C
#define QC4    300750       // QC/4
#define K      100
#define NBINS  2048         // top 11 bits of monotonic key (fallback path)
#define CAP    1024         // compact candidate capacity per batch
#define CAPSUB 64           // per-block region capacity (lambda~12.7, P(>64)~0)
#define BPB    32           // blocks per batch for the scan pass
#define BS     256
#define TLOGIT 3.4f         // fast-path collect threshold (exp ~405/batch for N(0,1))

// monotonic uint key: key increasing <=> float increasing
__device__ __forceinline__ unsigned int mono_key(float x) {
    unsigned int u = __float_as_uint(x);
    return u ^ ((u >> 31) ? 0xFFFFFFFFu : 0x80000000u);
}
__device__ __forceinline__ float key_to_float(unsigned int k) {
    unsigned int u = (k & 0x80000000u) ? (k ^ 0x80000000u) : ~k;
    return __uint_as_float(u);
}

// Fast path: single full read; collect candidates >= fixed logit threshold
// into this block's private region, counted by an LDS counter. Every block
// writes its bcnt slot unconditionally -> NO pre-zero kernel needed.
__global__ void __launch_bounds__(BS) pass1_kernel(const float* __restrict__ logits,
                                                   unsigned int* __restrict__ bcnt,
                                                   uint2* __restrict__ cand) {
    int b   = blockIdx.x / BPB;
    int sub = blockIdx.x % BPB;
    __shared__ unsigned int lcnt;
    if (threadIdx.x == 0) lcnt = 0u;
    __syncthreads();
    const float4* src = (const float4*)(logits + (size_t)b * QC);
    uint2* cb = cand + ((size_t)b * BPB + sub) * CAPSUB;
    for (int i = sub * BS + threadIdx.x; i < QC4; i += BPB * BS) {
        float4 v = src[i];
        unsigned int base = 4u * (unsigned int)i;
        if (v.x >= TLOGIT) { unsigned int s = atomicAdd(&lcnt, 1u); if (s < CAPSUB) cb[s] = make_uint2(mono_key(v.x), base + 0u); }
        if (v.y >= TLOGIT) { unsigned int s = atomicAdd(&lcnt, 1u); if (s < CAPSUB) cb[s] = make_uint2(mono_key(v.y), base + 1u); }
        if (v.z >= TLOGIT) { unsigned int s = atomicAdd(&lcnt, 1u); if (s < CAPSUB) cb[s] = make_uint2(mono_key(v.z), base + 2u); }
        if (v.w >= TLOGIT) { unsigned int s = atomicAdd(&lcnt, 1u); if (s < CAPSUB) cb[s] = make_uint2(mono_key(v.w), base + 3u); }
    }
    __syncthreads();
    if (threadIdx.x == 0) bcnt[b * BPB + sub] = lcnt;
}

// One block per batch. Validate per-block counts; compact regions into cand2
// and write cnt. If invalid (region overflow / total out of [K,CAP]):
// exact block-local histogram select over this batch (never taken for this
// workload's statistics, kept for exactness).
__global__ void __launch_bounds__(BS) compact_kernel(const float* __restrict__ logits,
                                                     const unsigned int* __restrict__ bcnt,
                                                     const uint2* __restrict__ cand,
                                                     unsigned int* __restrict__ cnt,
                                                     uint2* __restrict__ cand2) {
    int b = blockIdx.x;
    __shared__ unsigned int cnts[BPB];
    __shared__ unsigned int offs[BPB + 1];
    __shared__ int valid_s;
    if (threadIdx.x < BPB) cnts[threadIdx.x] = bcnt[b * BPB + threadIdx.x];
    __syncthreads();
    if (threadIdx.x == 0) {
        unsigned int tot = 0; int ok = 1;
        for (int j = 0; j < BPB; ++j) {
            unsigned int c = cnts[j];
            if (c > (unsigned int)CAPSUB) ok = 0;
            offs[j] = tot;
            tot += (c > (unsigned int)CAPSUB) ? (unsigned int)CAPSUB : c;
        }
        offs[BPB] = tot;
        if (tot < (unsigned int)K || tot > (unsigned int)CAP) ok = 0;
        valid_s = ok;
        if (ok) cnt[b] = tot;
    }
    __syncthreads();
    if (valid_s) {
        const uint2* cb = cand + (size_t)b * (BPB * CAPSUB);
        uint2* co = cand2 + (size_t)b * CAP;
        for (int idx = threadIdx.x; idx < BPB * CAPSUB; idx += BS) {
            int j = idx >> 6;           // CAPSUB = 64
            int i = idx & (CAPSUB - 1);
            if ((unsigned int)i < cnts[j]) co[offs[j] + i] = cb[idx];
        }
        return;
    }

    // ---- exact fallback: block-local histogram over this batch ----
    __shared__ unsigned int lh[NBINS];
    __shared__ uint2 sc[CAP];
    __shared__ unsigned int sn;
    __shared__ unsigned int tk_s;
    for (int i = threadIdx.x; i < NBINS; i += BS) lh[i] = 0u;
    __syncthreads();
    const float4* src = (const float4*)(logits + (size_t)b * QC);
    for (int i = threadIdx.x; i < QC4; i += BS) {
        float4 v = src[i];
        atomicAdd(&lh[mono_key(v.x) >> 21], 1u);
        atomicAdd(&lh[mono_key(v.y) >> 21], 1u);
        atomicAdd(&lh[mono_key(v.z) >> 21], 1u);
        atomicAdd(&lh[mono_key(v.w) >> 21], 1u);
    }
    __syncthreads();
    if (threadIdx.x == 0) {
        unsigned int cum = 0;
        int tb = 0;
        for (int i = NBINS - 1; i >= 0; --i) {
            cum += lh[i];
            if (cum >= (unsigned int)K) { tb = i; break; }
        }
        tk_s = ((unsigned int)tb) << 21;
        sn = 0u;
    }
    __syncthreads();
    unsigned int tk = tk_s;
    for (int i = threadIdx.x; i < QC4; i += BS) {
        float4 v = src[i];
        unsigned int base = 4u * (unsigned int)i;
        unsigned int k0 = mono_key(v.x);
        unsigned int k1 = mono_key(v.y);
        unsigned int k2 = mono_key(v.z);
        unsigned int k3 = mono_key(v.w);
        if (k0 >= tk) { unsigned int s = atomicAdd(&sn, 1u); if (s < CAP) sc[s] = make_uint2(k0, base + 0u); }
        if (k1 >= tk) { unsigned int s = atomicAdd(&sn, 1u); if (s < CAP) sc[s] = make_uint2(k1, base + 1u); }
        if (k2 >= tk) { unsigned int s = atomicAdd(&sn, 1u); if (s < CAP) sc[s] = make_uint2(k2, base + 2u); }
        if (k3 >= tk) { unsigned int s = atomicAdd(&sn, 1u); if (s < CAP) sc[s] = make_uint2(k3, base + 3u); }
    }
    __syncthreads();
    unsigned int m = sn;
    if (m > CAP) m = CAP;
    uint2* co = cand2 + (size_t)b * CAP;
    for (unsigned int i = threadIdx.x; i < m; i += BS) co[i] = sc[i];
    if (threadIdx.x == 0) cnt[b] = m;
}

// Exact top-K among candidates: rank by (key desc, idx asc); write outputs.
// BYTE-IDENTICAL to the proven baseline output_kernel.
__global__ void __launch_bounds__(BS) output_kernel(const unsigned int* __restrict__ cnt,
                                                    const uint2* __restrict__ cand,
                                                    const float* __restrict__ bbox,
                                                    const float* __restrict__ tsizes,
                                                    float* __restrict__ out) {
    __shared__ uint2 sc[CAP];
    int b = blockIdx.x;
    unsigned int n = cnt[b];
    if (n > CAP) n = CAP;
    const uint2* cb = cand + (size_t)b * CAP;
    for (unsigned int i = threadIdx.x; i < n; i += BS) sc[i] = cb[i];
    __syncthreads();
    float img_h = tsizes[2 * b + 0];
    float img_w = tsizes[2 * b + 1];
    float* scores = out;
    float* labels = out + NBATCH * K;
    float* boxes  = out + 2 * NBATCH * K;
    for (unsigned int i = threadIdx.x; i < n; i += BS) {
        uint2 me = sc[i];
        int rank = 0;
        for (unsigned int j = 0; j < n; ++j) {
            uint2 o = sc[j];
            if (o.x > me.x || (o.x == me.x && o.y < me.y)) rank++;
        }
        if (rank < K) {
            float v = key_to_float(me.x);
            double sd = 1.0 / (1.0 + exp(-(double)v));
            scores[b * K + rank] = (float)sd;
            unsigned int idx = me.y;
            unsigned int q   = idx / C;
            unsigned int lab = idx - q * C;
            labels[b * K + rank] = (float)lab;
            const float* bb = bbox + ((size_t)b * Q + q) * 4;
            float cx = bb[0], cy = bb[1], w = bb[2], h = bb[3];
            float* o = boxes + ((size_t)b * K + (size_t)rank) * 4;
            o[0] = (cx - 0.5f * w) * img_w;
            o[1] = (cy - 0.5f * h) * img_h;
            o[2] = (cx + 0.5f * w) * img_w;
            o[3] = (cy + 0.5f * h) * img_h;
        }
    }
}

extern "C" void kernel_launch(void* const* d_in, const int* in_sizes, int n_in,
                              void* d_out, int out_size, void* d_ws, size_t ws_size,
                              hipStream_t stream) {
    const float* logits = (const float*)d_in[0];   // 64*1000*1203
    const float* bbox   = (const float*)d_in[1];   // 64*1000*4
    const float* tsizes = (const float*)d_in[2];   // 64*2
    float* out = (float*)d_out;

    char* ws = (char*)d_ws;
    unsigned int* cnt   = (unsigned int*)(ws);                 // 256 B
    unsigned int* bcnt  = (unsigned int*)(ws + 4096);          // 8 KiB (64*32)
    uint2*        cand2 = (uint2*)(ws + 16384);                // 512 KiB compact
    uint2*        cand  = (uint2*)(ws + 16384 + 524288);       // 1 MiB regions

    pass1_kernel<<<NBATCH * BPB, BS, 0, stream>>>(logits, bcnt, cand);
    compact_kernel<<<NBATCH, BS, 0, stream>>>(logits, bcnt, cand, cnt, cand2);
    output_kernel<<<NBATCH, BS, 0, stream>>>(cnt, cand2, bbox, tsizes, out);
}